// Round 6
// baseline (238.040 us; speedup 1.0000x reference)
//
#include <hip/hip_runtime.h>

typedef unsigned short u16;
typedef __attribute__((ext_vector_type(4))) float f32x4;
typedef __attribute__((ext_vector_type(8))) short s16x8;
typedef __attribute__((ext_vector_type(4))) unsigned short u16x4;
typedef __attribute__((ext_vector_type(2))) unsigned int u32x2;

#define S_ 2048
#define D_ 1024
#define H_ 16
#define KH 64
#define M_ 4096   // B*S
#define BH_ 32    // B*H

__device__ __forceinline__ float bf2f(u16 v) {
    union { unsigned int u; float f; } x; x.u = ((unsigned int)v) << 16; return x.f;
}
__device__ __forceinline__ u16 f2bf(float f) {
    union { float ff; unsigned int u; } x; x.ff = f;
    unsigned int r = x.u + 0x7fffu + ((x.u >> 16) & 1u);
    return (u16)(r >> 16);
}
__device__ __forceinline__ unsigned int cvt_pk_bf16(float lo, float hi) {
    unsigned int d;
    asm("v_cvt_pk_bf16_f32 %0, %1, %2" : "=v"(d) : "v"(lo), "v"(hi));
    return d;
}

// ---------------------------------------------------------------------------
// x (fp32, 4096x1024) -> xb (bf16)
// ---------------------------------------------------------------------------
__global__ void kcvt_x(const float* __restrict__ x, u16* __restrict__ xb) {
    const int i = (blockIdx.x * 256 + threadIdx.x) * 4;
    const float4 v = *(const float4*)&x[i];
    u16x4 o;
    o.x = f2bf(v.x); o.y = f2bf(v.y); o.z = f2bf(v.z); o.w = f2bf(v.w);
    *(u16x4*)&xb[i] = o;
}

// ---------------------------------------------------------------------------
// Weight pack (fp32 src -> bf16 dst):
//   mats 0-2: Wt[n*1024+d] = W[h=n>>6][d][k=n&63]  (n = h*64+k)
//   mat  3 : WtO[dc*1024+n] = W_O[n*1024+dc]
// ---------------------------------------------------------------------------
__global__ void ktrans_w(const float* __restrict__ WQ, const float* __restrict__ WK,
                         const float* __restrict__ WV, const float* __restrict__ WO,
                         u16* __restrict__ wt) {
    __shared__ u16 tile[64][65];
    const int mat = blockIdx.z;
    const float* src = (mat == 0) ? WQ : (mat == 1) ? WK : (mat == 2) ? WV : WO;
    u16* dst = wt + (size_t)mat * 1048576;
    const int a0 = blockIdx.x * 64, b0 = blockIdx.y * 64;
    const int t = threadIdx.x;
    const int bl = t & 63, ar = t >> 6;
    #pragma unroll
    for (int i = 0; i < 16; ++i) {
        int a = a0 + i * 4 + ar, b = b0 + bl;
        size_t sa = (mat < 3) ? (((size_t)(b >> 6)) << 16) + ((size_t)a << 6) + (b & 63)
                              : (size_t)a * 1024 + b;
        tile[i * 4 + ar][bl] = f2bf(src[sa]);
    }
    __syncthreads();
    #pragma unroll
    for (int i = 0; i < 16; ++i) {
        int bl2 = i * 4 + ar;
        dst[(size_t)(b0 + bl2) * 1024 + a0 + bl] = tile[bl][bl2];
    }
}

// ---------------------------------------------------------------------------
// QKV GEMM: 128x128 tile, BK=32, 4 waves (2x2).
// z=0/1 (Q/K): swapped MFMA -> lane holds 4 consecutive cols -> 8B stores to
//              (BH,S,64). z=2 (V): unswapped MFMA -> lane holds 4 consecutive
//              rows (s) -> 8B stores directly into Vt (BH,64,S).
// ---------------------------------------------------------------------------
__global__ __launch_bounds__(256)
void kgemm0(const u16* __restrict__ A, const u16* __restrict__ Wt,
            const float* __restrict__ b0p, const float* __restrict__ b1p,
            const float* __restrict__ b2p,
            u16* __restrict__ Qo, u16* __restrict__ Ko, u16* __restrict__ Vto) {
    __shared__ u16 As[2][128 * 32];
    __shared__ u16 Bs[2][128 * 32];
    const int t = threadIdx.x;
    const int l = t & 63, w = t >> 6;
    const int lq = l & 15, lg = l >> 4;
    const int wr = w >> 1, wc = w & 1;
    const int m0 = blockIdx.x * 128;
    const int n0 = blockIdx.y * 128;
    const int z = blockIdx.z;
    const u16* Bt = Wt + (size_t)z * 1048576;
    const float* bias = (z == 0) ? b0p : (z == 1) ? b1p : b2p;

    f32x4 acc[4][4] = {};

    auto stage = [&](int kt, int buf) {
        #pragma unroll
        for (int i = 0; i < 2; ++i) {
            int idx = t + i * 256;
            int row = idx >> 2, cc = idx & 3;
            const u16* ga = A + (size_t)(m0 + row) * 1024 + kt * 32 + cc * 8;
            const u16* gb = Bt + (size_t)(n0 + row) * 1024 + kt * 32 + cc * 8;
            __builtin_amdgcn_global_load_lds(
                (const __attribute__((address_space(1))) unsigned int*)ga,
                (__attribute__((address_space(3))) unsigned int*)(&As[buf][idx * 8]),
                16, 0, 0);
            __builtin_amdgcn_global_load_lds(
                (const __attribute__((address_space(1))) unsigned int*)gb,
                (__attribute__((address_space(3))) unsigned int*)(&Bs[buf][idx * 8]),
                16, 0, 0);
        }
    };

    stage(0, 0);
    __syncthreads();
    for (int kt = 0; kt < 32; ++kt) {
        const int cur = kt & 1;
        if (kt + 1 < 32) stage(kt + 1, cur ^ 1);
        s16x8 af[4], bf[4];
        #pragma unroll
        for (int m = 0; m < 4; ++m)
            af[m] = *(const s16x8*)&As[cur][(wr * 64 + m * 16 + lq) * 32 + lg * 8];
        #pragma unroll
        for (int n = 0; n < 4; ++n)
            bf[n] = *(const s16x8*)&Bs[cur][(wc * 64 + n * 16 + lq) * 32 + lg * 8];
        if (z == 2) {
            #pragma unroll
            for (int m = 0; m < 4; ++m)
                #pragma unroll
                for (int n = 0; n < 4; ++n)
                    acc[m][n] = __builtin_amdgcn_mfma_f32_16x16x32_bf16(
                        af[m], bf[n], acc[m][n], 0, 0, 0);   // row=s frag-local
        } else {
            #pragma unroll
            for (int m = 0; m < 4; ++m)
                #pragma unroll
                for (int n = 0; n < 4; ++n)
                    acc[m][n] = __builtin_amdgcn_mfma_f32_16x16x32_bf16(
                        bf[n], af[m], acc[m][n], 0, 0, 0);   // col=kk frag-local
        }
        __syncthreads();
    }

    if (z == 2) {
        // acc[m][n][r] = C[row = m0+wr*64+m*16+lg*4+r][col = n0+wc*64+n*16+lq]
        #pragma unroll
        for (int n = 0; n < 4; ++n) {
            const int gcol = n0 + wc * 64 + n * 16 + lq;
            const float bv = bias[gcol];
            const int h = gcol >> 6, kk = gcol & 63;
            #pragma unroll
            for (int m = 0; m < 4; ++m) {
                const int growb = m0 + wr * 64 + m * 16 + lg * 4;
                const int b = growb >> 11, s = growb & 2047;
                u32x2 wp;
                wp.x = cvt_pk_bf16(acc[m][n][0] + bv, acc[m][n][1] + bv);
                wp.y = cvt_pk_bf16(acc[m][n][2] + bv, acc[m][n][3] + bv);
                *(u32x2*)&Vto[(size_t)((b * 16 + h) * 64 + kk) * 2048 + s] = wp;
            }
        }
    } else {
        // acc[m][n][r] = C[col = n0+wc*64+n*16+lg*4+r][row = m0+wr*64+m*16+lq]
        u16* outp = (z == 0) ? Qo : Ko;
        #pragma unroll
        for (int n = 0; n < 4; ++n) {
            const int gcolb = n0 + wc * 64 + n * 16 + lg * 4;
            const float4 bv = *(const float4*)&bias[gcolb];
            const int h = gcolb >> 6, kk0 = gcolb & 63;
            #pragma unroll
            for (int m = 0; m < 4; ++m) {
                const int grow = m0 + wr * 64 + m * 16 + lq;
                const int b = grow >> 11, s = grow & 2047;
                u32x2 wp;
                wp.x = cvt_pk_bf16(acc[m][n][0] + bv.x, acc[m][n][1] + bv.y);
                wp.y = cvt_pk_bf16(acc[m][n][2] + bv.z, acc[m][n][3] + bv.w);
                *(u32x2*)&outp[((size_t)(b * 16 + h) * 2048 + s) * 64 + kk0] = wp;
            }
        }
    }
}

// ---------------------------------------------------------------------------
// Output GEMM: out = Z(4096x1024) * WtO^T + bO, fp32 out.
// BM=128, BN=64 -> grid (32,16)=512 blocks = 2/CU. Swapped MFMA -> float4.
// ---------------------------------------------------------------------------
__global__ __launch_bounds__(256)
void kgemm1(const u16* __restrict__ A, const u16* __restrict__ Bt,
            const float* __restrict__ bias, float* __restrict__ fo) {
    __shared__ u16 As[2][128 * 32];
    __shared__ u16 Bs[2][64 * 32];
    const int t = threadIdx.x;
    const int l = t & 63, w = t >> 6;
    const int lq = l & 15, lg = l >> 4;
    const int wr = w >> 1, wc = w & 1;
    const int m0 = blockIdx.x * 128;
    const int n0 = blockIdx.y * 64;

    f32x4 acc[4][2] = {};

    auto stage = [&](int kt, int buf) {
        #pragma unroll
        for (int i = 0; i < 2; ++i) {
            int idx = t + i * 256;
            int row = idx >> 2, cc = idx & 3;
            __builtin_amdgcn_global_load_lds(
                (const __attribute__((address_space(1))) unsigned int*)
                    (A + (size_t)(m0 + row) * 1024 + kt * 32 + cc * 8),
                (__attribute__((address_space(3))) unsigned int*)(&As[buf][idx * 8]),
                16, 0, 0);
        }
        {
            int row = t >> 2, cc = t & 3;
            __builtin_amdgcn_global_load_lds(
                (const __attribute__((address_space(1))) unsigned int*)
                    (Bt + (size_t)(n0 + row) * 1024 + kt * 32 + cc * 8),
                (__attribute__((address_space(3))) unsigned int*)(&Bs[buf][t * 8]),
                16, 0, 0);
        }
    };

    stage(0, 0);
    __syncthreads();
    for (int kt = 0; kt < 32; ++kt) {
        const int cur = kt & 1;
        if (kt + 1 < 32) stage(kt + 1, cur ^ 1);
        s16x8 af[4], bf[2];
        #pragma unroll
        for (int m = 0; m < 4; ++m)
            af[m] = *(const s16x8*)&As[cur][(wr * 64 + m * 16 + lq) * 32 + lg * 8];
        #pragma unroll
        for (int n = 0; n < 2; ++n)
            bf[n] = *(const s16x8*)&Bs[cur][(wc * 32 + n * 16 + lq) * 32 + lg * 8];
        #pragma unroll
        for (int m = 0; m < 4; ++m)
            #pragma unroll
            for (int n = 0; n < 2; ++n)
                acc[m][n] = __builtin_amdgcn_mfma_f32_16x16x32_bf16(
                    bf[n], af[m], acc[m][n], 0, 0, 0);
        __syncthreads();
    }

    #pragma unroll
    for (int n = 0; n < 2; ++n) {
        const int gcolb = n0 + wc * 32 + n * 16 + lg * 4;
        const float4 bv = *(const float4*)&bias[gcolb];
        #pragma unroll
        for (int m = 0; m < 4; ++m) {
            const int grow = m0 + wr * 64 + m * 16 + lq;
            float4 o;
            o.x = acc[m][n][0] + bv.x;
            o.y = acc[m][n][1] + bv.y;
            o.z = acc[m][n][2] + bv.z;
            o.w = acc[m][n][3] + bv.w;
            *(float4*)&fo[(size_t)grow * 1024 + gcolb] = o;
        }
    }
}

// ---------------------------------------------------------------------------
// Flash attention, cross-step software pipeline: QK(t+1) issued at end of
// step t (after barrier), so softmax(t+1) consumes a phase-old MFMA result
// and the MFMA pipe (PV(t), QK(t+1)) drains under the next softmax's VALU.
// grid 512 linear; XCD-local decode (lin%8 == bh%8). 33 steps/block.
// ---------------------------------------------------------------------------
__global__ __launch_bounds__(256)
void kattn(const u16* __restrict__ Q, const u16* __restrict__ K,
           const u16* __restrict__ Vt, u16* __restrict__ Z) {
    __shared__ u16 Ks[2][64 * 64];
    __shared__ u16 Vs[2][64 * 64];
    __shared__ u16 Pl[4][16 * 72];
    const int t = threadIdx.x, l = t & 63, w = t >> 6;
    const int lq = l & 15, lg = l >> 4;

    const int lin = blockIdx.x + 16 * blockIdx.y;
    const int xcd = lin & 7;
    const int idx = lin >> 3;
    const int pair = idx & 15;
    const int bh = xcd + 8 * (idx >> 4);

    const size_t base = (size_t)bh * (S_ * KH);
    const u16* Qb = Q + base;
    const u16* Kb = K + base;
    const u16* Vb = Vt + base;
    const int b = bh >> 4, h = bh & 15;
    u16* Pw = &Pl[w][0];

    const int c0 = ((lg ^ (lq & 7)) * 8);
    const int c1 = c0 ^ 32;
    const float NINF = -__builtin_inff();
    const float SCL = 0.18033688011112042f;   // 0.125 * log2(e)

    auto stage = [&](int k0, int buf) {
        #pragma unroll
        for (int i = 0; i < 2; ++i) {
            const int idx2 = t + i * 256;
            const int row = idx2 >> 3;
            const int cg = (idx2 & 7) ^ (row & 7);
            __builtin_amdgcn_global_load_lds(
                (const __attribute__((address_space(1))) unsigned int*)
                    (Kb + (size_t)(k0 + row) * KH + cg * 8),
                (__attribute__((address_space(3))) unsigned int*)(&Ks[buf][idx2 * 8]),
                16, 0, 0);
            __builtin_amdgcn_global_load_lds(
                (const __attribute__((address_space(1))) unsigned int*)
                    (Vb + (size_t)row * S_ + k0 + cg * 8),
                (__attribute__((address_space(3))) unsigned int*)(&Vs[buf][idx2 * 8]),
                16, 0, 0);
        }
    };

    #pragma unroll 1
    for (int ph = 0; ph < 2; ++ph) {
        const int qt = ph ? (31 - pair) : pair;
        const int nt = qt + 1;
        const int qs = qt * 64 + w * 16;
        const int lim = w * 16 + lq;

        const s16x8 qf0 = *(const s16x8*)&Qb[(size_t)(qs + lq) * KH + lg * 8];
        const s16x8 qf1 = *(const s16x8*)&Qb[(size_t)(qs + lq) * KH + 32 + lg * 8];

        float mrow = NINF, lrow = 0.f;
        f32x4 zacc[4] = {};
        f32x4 sfA[4], sfB[4];

        auto QK = [&](int buf, f32x4 (&sfo)[4]) {
            __builtin_amdgcn_s_setprio(1);
            #pragma unroll
            for (int kf = 0; kf < 4; ++kf) {
                const int row = kf * 16 + lq;
                const s16x8 ka = *(const s16x8*)&Ks[buf][row * 64 + c0];
                const s16x8 kb = *(const s16x8*)&Ks[buf][row * 64 + c1];
                f32x4 z4 = {};
                z4 = __builtin_amdgcn_mfma_f32_16x16x32_bf16(ka, qf0, z4, 0, 0, 0);
                sfo[kf] = __builtin_amdgcn_mfma_f32_16x16x32_bf16(kb, qf1, z4, 0, 0, 0);
            }
            __builtin_amdgcn_s_setprio(0);
        };

        auto STEP = [&](f32x4 (&sfc)[4], f32x4 (&sfn)[4], int kt) {
            const int buf = kt & 1;
            const bool hn = (kt + 1 < nt);
            if (hn) stage((kt + 1) * 64, buf ^ 1);

            // lane holds S[k=16kf+4lg+r][q=lq] (log2 domain after scale)
            float p[4][4];
            const bool diag = (kt == qt);
            #pragma unroll
            for (int kf = 0; kf < 4; ++kf)
                #pragma unroll
                for (int r = 0; r < 4; ++r) {
                    float v = sfc[kf][r] * SCL;
                    if (diag && (kf * 16 + lg * 4 + r) > lim) v = NINF;
                    p[kf][r] = v;
                }

            float mk[4];
            #pragma unroll
            for (int kf = 0; kf < 4; ++kf)
                mk[kf] = fmaxf(fmaxf(p[kf][0], p[kf][1]), fmaxf(p[kf][2], p[kf][3]));
            float tmax = fmaxf(fmaxf(mk[0], mk[1]), fmaxf(mk[2], mk[3]));
            tmax = fmaxf(tmax, __shfl_xor(tmax, 16));
            tmax = fmaxf(tmax, __shfl_xor(tmax, 32));

            float alpha = 1.f;
            if (!__all(tmax <= mrow + 8.f)) {
                const float nm = fmaxf(mrow, tmax);
                alpha = exp2f(mrow - nm);
                mrow = nm;
                #pragma unroll
                for (int nf = 0; nf < 4; ++nf)
                    #pragma unroll
                    for (int r = 0; r < 4; ++r)
                        zacc[nf][r] *= alpha;
            }

            float sk[4];
            #pragma unroll
            for (int kf = 0; kf < 4; ++kf) {
                #pragma unroll
                for (int r = 0; r < 4; ++r)
                    p[kf][r] = exp2f(p[kf][r] - mrow);
                sk[kf] = (p[kf][0] + p[kf][1]) + (p[kf][2] + p[kf][3]);
            }
            float rsum = (sk[0] + sk[1]) + (sk[2] + sk[3]);
            rsum += __shfl_xor(rsum, 16);
            rsum += __shfl_xor(rsum, 32);
            lrow = lrow * alpha + rsum;

            #pragma unroll
            for (int kf = 0; kf < 4; ++kf) {
                u32x2 wp;
                wp.x = cvt_pk_bf16(p[kf][0], p[kf][1]);
                wp.y = cvt_pk_bf16(p[kf][2], p[kf][3]);
                *(u32x2*)&Pw[lq * 72 + kf * 16 + lg * 4] = wp;
            }
            const s16x8 pa0 = *(const s16x8*)&Pw[lq * 72 + lg * 8];
            const s16x8 pa1 = *(const s16x8*)&Pw[lq * 72 + 32 + lg * 8];

            __builtin_amdgcn_s_setprio(1);
            #pragma unroll
            for (int nf = 0; nf < 4; ++nf) {
                const int row = nf * 16 + lq;
                const s16x8 v0 = *(const s16x8*)&Vs[buf][row * 64 + c0];
                const s16x8 v1 = *(const s16x8*)&Vs[buf][row * 64 + c1];
                zacc[nf] = __builtin_amdgcn_mfma_f32_16x16x32_bf16(v0, pa0, zacc[nf], 0, 0, 0);
                zacc[nf] = __builtin_amdgcn_mfma_f32_16x16x32_bf16(v1, pa1, zacc[nf], 0, 0, 0);
            }
            __builtin_amdgcn_s_setprio(0);
            __syncthreads();          // stage(kt+1) landed; buf free for reuse
            if (hn) QK(buf ^ 1, sfn); // next tile's scores, one phase early
        };

        stage(0, 0);
        __syncthreads();
        QK(0, sfA);
        for (int kt = 0; kt < nt; kt += 2) {
            STEP(sfA, sfB, kt);
            if (kt + 1 < nt) STEP(sfB, sfA, kt + 1);
        }

        // zacc[nf][r] = z[q=lq][d=nf*16+lg*4+r]; lrow lane-local
        const float rinv = 1.f / lrow;
        const size_t zrow = (size_t)(b * S_ + qs + lq) * 1024 + h * 64;
        #pragma unroll
        for (int nf = 0; nf < 4; ++nf) {
            u32x2 wp;
            wp.x = cvt_pk_bf16(zacc[nf][0] * rinv, zacc[nf][1] * rinv);
            wp.y = cvt_pk_bf16(zacc[nf][2] * rinv, zacc[nf][3] * rinv);
            *(u32x2*)&Z[zrow + nf * 16 + lg * 4] = wp;
        }
    }
}

// ---------------------------------------------------------------------------
extern "C" void kernel_launch(void* const* d_in, const int* in_sizes, int n_in,
                              void* d_out, int out_size, void* d_ws, size_t ws_size,
                              hipStream_t stream) {
    const float* x  = (const float*)d_in[0];
    const float* WQ = (const float*)d_in[1];
    const float* WK = (const float*)d_in[2];
    const float* WV = (const float*)d_in[3];
    const float* WO = (const float*)d_in[4];
    const float* bQ = (const float*)d_in[5];
    const float* bK = (const float*)d_in[6];
    const float* bV = (const float*)d_in[7];
    const float* bO = (const float*)d_in[8];
    float* out = (float*)d_out;

    u16* ws  = (u16*)d_ws;
    u16* xb  = ws;
    u16* wt  = xb + 4194304u;
    u16* Qb  = wt + 4194304u;
    u16* Kb  = Qb + 4194304u;
    u16* Vtb = Kb + 4194304u;
    u16* Zb  = Vtb + 4194304u;

    kcvt_x<<<dim3(4096), 256, 0, stream>>>(x, xb);
    ktrans_w<<<dim3(16, 16, 4), 256, 0, stream>>>(WQ, WK, WV, WO, wt);
    kgemm0<<<dim3(32, 8, 3), 256, 0, stream>>>(
        xb, wt, bQ, bK, bV, Qb, Kb, Vtb);
    kattn<<<dim3(16, BH_), 256, 0, stream>>>(Qb, Kb, Vtb, Zb);
    kgemm1<<<dim3(32, 16), 256, 0, stream>>>(
        Zb, wt + 3u * 1048576u, bO, out);
}

// Round 7
// 222.968 us; speedup vs baseline: 1.0676x; 1.0676x over previous
//
#include <hip/hip_runtime.h>

typedef unsigned short u16;
typedef __attribute__((ext_vector_type(4))) float f32x4;
typedef __attribute__((ext_vector_type(8))) short s16x8;
typedef __attribute__((ext_vector_type(4))) unsigned short u16x4;
typedef __attribute__((ext_vector_type(2))) unsigned int u32x2;

#define S_ 2048
#define D_ 1024
#define H_ 16
#define KH 64
#define M_ 4096   // B*S
#define BH_ 32    // B*H

__device__ __forceinline__ float bf2f(u16 v) {
    union { unsigned int u; float f; } x; x.u = ((unsigned int)v) << 16; return x.f;
}
__device__ __forceinline__ u16 f2bf(float f) {
    union { float ff; unsigned int u; } x; x.ff = f;
    unsigned int r = x.u + 0x7fffu + ((x.u >> 16) & 1u);
    return (u16)(r >> 16);
}
__device__ __forceinline__ unsigned int cvt_pk_bf16(float lo, float hi) {
    unsigned int d;
    asm("v_cvt_pk_bf16_f32 %0, %1, %2" : "=v"(d) : "v"(lo), "v"(hi));
    return d;
}

// ---------------------------------------------------------------------------
// x (fp32, 4096x1024) -> xb (bf16)
// ---------------------------------------------------------------------------
__global__ void kcvt_x(const float* __restrict__ x, u16* __restrict__ xb) {
    const int i = (blockIdx.x * 256 + threadIdx.x) * 4;
    const float4 v = *(const float4*)&x[i];
    u16x4 o;
    o.x = f2bf(v.x); o.y = f2bf(v.y); o.z = f2bf(v.z); o.w = f2bf(v.w);
    *(u16x4*)&xb[i] = o;
}

// ---------------------------------------------------------------------------
// Weight pack (fp32 src -> bf16 dst):
//   mats 0-2: Wt[n*1024+d] = W[h=n>>6][d][k=n&63]  (n = h*64+k)
//   mat  3 : WtO[dc*1024+n] = W_O[n*1024+dc]
// ---------------------------------------------------------------------------
__global__ void ktrans_w(const float* __restrict__ WQ, const float* __restrict__ WK,
                         const float* __restrict__ WV, const float* __restrict__ WO,
                         u16* __restrict__ wt) {
    __shared__ u16 tile[64][65];
    const int mat = blockIdx.z;
    const float* src = (mat == 0) ? WQ : (mat == 1) ? WK : (mat == 2) ? WV : WO;
    u16* dst = wt + (size_t)mat * 1048576;
    const int a0 = blockIdx.x * 64, b0 = blockIdx.y * 64;
    const int t = threadIdx.x;
    const int bl = t & 63, ar = t >> 6;
    #pragma unroll
    for (int i = 0; i < 16; ++i) {
        int a = a0 + i * 4 + ar, b = b0 + bl;
        size_t sa = (mat < 3) ? (((size_t)(b >> 6)) << 16) + ((size_t)a << 6) + (b & 63)
                              : (size_t)a * 1024 + b;
        tile[i * 4 + ar][bl] = f2bf(src[sa]);
    }
    __syncthreads();
    #pragma unroll
    for (int i = 0; i < 16; ++i) {
        int bl2 = i * 4 + ar;
        dst[(size_t)(b0 + bl2) * 1024 + a0 + bl] = tile[bl][bl2];
    }
}

// ---------------------------------------------------------------------------
// QKV GEMM, template-split (single MFMA path per instantiation).
// VM=0 (Q/K, blockIdx.z=0/1): swapped MFMA -> lane holds 4 consecutive output
//       cols (kk) -> packed 8B stores to (BH,S,64).
// VM=1 (V): unswapped MFMA -> lane holds 4 consecutive rows (s) -> packed 8B
//       stores directly into Vt (BH,64,S).
// ---------------------------------------------------------------------------
template <int VM>
__global__ __launch_bounds__(256)
void kgemm0t(const u16* __restrict__ A, const u16* __restrict__ Wt,
             const float* __restrict__ b0p, const float* __restrict__ b1p,
             u16* __restrict__ o0, u16* __restrict__ o1) {
    __shared__ u16 As[2][128 * 32];
    __shared__ u16 Bs[2][128 * 32];
    const int t = threadIdx.x;
    const int l = t & 63, w = t >> 6;
    const int lq = l & 15, lg = l >> 4;
    const int wr = w >> 1, wc = w & 1;
    const int m0 = blockIdx.x * 128;
    const int n0 = blockIdx.y * 128;
    const int z = (VM == 0) ? blockIdx.z : 0;
    const u16* Bt = Wt + (size_t)z * 1048576;
    const float* bias = z ? b1p : b0p;
    u16* outp = z ? o1 : o0;

    f32x4 acc[4][4] = {};

    auto stage = [&](int kt, int buf) {
        #pragma unroll
        for (int i = 0; i < 2; ++i) {
            int idx = t + i * 256;
            int row = idx >> 2, cc = idx & 3;
            const u16* ga = A + (size_t)(m0 + row) * 1024 + kt * 32 + cc * 8;
            const u16* gb = Bt + (size_t)(n0 + row) * 1024 + kt * 32 + cc * 8;
            __builtin_amdgcn_global_load_lds(
                (const __attribute__((address_space(1))) unsigned int*)ga,
                (__attribute__((address_space(3))) unsigned int*)(&As[buf][idx * 8]),
                16, 0, 0);
            __builtin_amdgcn_global_load_lds(
                (const __attribute__((address_space(1))) unsigned int*)gb,
                (__attribute__((address_space(3))) unsigned int*)(&Bs[buf][idx * 8]),
                16, 0, 0);
        }
    };

    stage(0, 0);
    __syncthreads();
    for (int kt = 0; kt < 32; ++kt) {
        const int cur = kt & 1;
        if (kt + 1 < 32) stage(kt + 1, cur ^ 1);
        s16x8 af[4], bf[4];
        #pragma unroll
        for (int m = 0; m < 4; ++m)
            af[m] = *(const s16x8*)&As[cur][(wr * 64 + m * 16 + lq) * 32 + lg * 8];
        #pragma unroll
        for (int n = 0; n < 4; ++n)
            bf[n] = *(const s16x8*)&Bs[cur][(wc * 64 + n * 16 + lq) * 32 + lg * 8];
        #pragma unroll
        for (int m = 0; m < 4; ++m)
            #pragma unroll
            for (int n = 0; n < 4; ++n) {
                if constexpr (VM == 1)
                    acc[m][n] = __builtin_amdgcn_mfma_f32_16x16x32_bf16(
                        af[m], bf[n], acc[m][n], 0, 0, 0);   // row=s frag-local
                else
                    acc[m][n] = __builtin_amdgcn_mfma_f32_16x16x32_bf16(
                        bf[n], af[m], acc[m][n], 0, 0, 0);   // col=kk frag-local
            }
        __syncthreads();
    }

    if constexpr (VM == 1) {
        // acc[m][n][r] = C[row = m0+wr*64+m*16+lg*4+r][col = n0+wc*64+n*16+lq]
        #pragma unroll
        for (int n = 0; n < 4; ++n) {
            const int gcol = n0 + wc * 64 + n * 16 + lq;
            const float bv = bias[gcol];
            const int h = gcol >> 6, kk = gcol & 63;
            #pragma unroll
            for (int m = 0; m < 4; ++m) {
                const int growb = m0 + wr * 64 + m * 16 + lg * 4;
                const int b = growb >> 11, s = growb & 2047;
                u32x2 wp;
                wp.x = cvt_pk_bf16(acc[m][n][0] + bv, acc[m][n][1] + bv);
                wp.y = cvt_pk_bf16(acc[m][n][2] + bv, acc[m][n][3] + bv);
                *(u32x2*)&o0[(size_t)((b * 16 + h) * 64 + kk) * 2048 + s] = wp;
            }
        }
    } else {
        // acc[m][n][r] = C[col = n0+wc*64+n*16+lg*4+r][row = m0+wr*64+m*16+lq]
        #pragma unroll
        for (int n = 0; n < 4; ++n) {
            const int gcolb = n0 + wc * 64 + n * 16 + lg * 4;
            const float4 bv = *(const float4*)&bias[gcolb];
            const int h = gcolb >> 6, kk0 = gcolb & 63;
            #pragma unroll
            for (int m = 0; m < 4; ++m) {
                const int grow = m0 + wr * 64 + m * 16 + lq;
                const int b = grow >> 11, s = grow & 2047;
                u32x2 wp;
                wp.x = cvt_pk_bf16(acc[m][n][0] + bv.x, acc[m][n][1] + bv.y);
                wp.y = cvt_pk_bf16(acc[m][n][2] + bv.z, acc[m][n][3] + bv.w);
                *(u32x2*)&outp[((size_t)(b * 16 + h) * 2048 + s) * 64 + kk0] = wp;
            }
        }
    }
}

// ---------------------------------------------------------------------------
// Output GEMM: out = Z(4096x1024) * WtO^T + bO, fp32 out.
// BM=128, BN=64, 1-D grid 512 with XCD-local remap: each XCD owns 4 m-block
// rows -> A panel 1MB + B 2MB = 3MB fits XCD L2 (kills the 16x A re-read).
// ---------------------------------------------------------------------------
__global__ __launch_bounds__(256)
void kgemm1(const u16* __restrict__ A, const u16* __restrict__ Bt,
            const float* __restrict__ bias, float* __restrict__ fo) {
    __shared__ u16 As[2][128 * 32];
    __shared__ u16 Bs[2][64 * 32];
    const int t = threadIdx.x;
    const int l = t & 63, w = t >> 6;
    const int lq = l & 15, lg = l >> 4;
    const int wr = w >> 1, wc = w & 1;

    const int lin = blockIdx.x;          // 0..511
    const int xcd = lin & 7;
    const int s = lin >> 3;              // 0..63
    const int nb = s & 15;               // 16 n-blocks
    const int mb = (s >> 4) * 8 + xcd;   // 32 m-blocks, grouped per XCD
    const int m0 = mb * 128;
    const int n0 = nb * 64;

    f32x4 acc[4][2] = {};

    auto stage = [&](int kt, int buf) {
        #pragma unroll
        for (int i = 0; i < 2; ++i) {
            int idx = t + i * 256;
            int row = idx >> 2, cc = idx & 3;
            __builtin_amdgcn_global_load_lds(
                (const __attribute__((address_space(1))) unsigned int*)
                    (A + (size_t)(m0 + row) * 1024 + kt * 32 + cc * 8),
                (__attribute__((address_space(3))) unsigned int*)(&As[buf][idx * 8]),
                16, 0, 0);
        }
        {
            int row = t >> 2, cc = t & 3;
            __builtin_amdgcn_global_load_lds(
                (const __attribute__((address_space(1))) unsigned int*)
                    (Bt + (size_t)(n0 + row) * 1024 + kt * 32 + cc * 8),
                (__attribute__((address_space(3))) unsigned int*)(&Bs[buf][t * 8]),
                16, 0, 0);
        }
    };

    stage(0, 0);
    __syncthreads();
    for (int kt = 0; kt < 32; ++kt) {
        const int cur = kt & 1;
        if (kt + 1 < 32) stage(kt + 1, cur ^ 1);
        s16x8 af[4], bf[2];
        #pragma unroll
        for (int m = 0; m < 4; ++m)
            af[m] = *(const s16x8*)&As[cur][(wr * 64 + m * 16 + lq) * 32 + lg * 8];
        #pragma unroll
        for (int n = 0; n < 2; ++n)
            bf[n] = *(const s16x8*)&Bs[cur][(wc * 32 + n * 16 + lq) * 32 + lg * 8];
        #pragma unroll
        for (int m = 0; m < 4; ++m)
            #pragma unroll
            for (int n = 0; n < 2; ++n)
                acc[m][n] = __builtin_amdgcn_mfma_f32_16x16x32_bf16(
                    bf[n], af[m], acc[m][n], 0, 0, 0);
        __syncthreads();
    }

    #pragma unroll
    for (int n = 0; n < 2; ++n) {
        const int gcolb = n0 + wc * 32 + n * 16 + lg * 4;
        const float4 bv = *(const float4*)&bias[gcolb];
        #pragma unroll
        for (int m = 0; m < 4; ++m) {
            const int grow = m0 + wr * 64 + m * 16 + lq;
            float4 o;
            o.x = acc[m][n][0] + bv.x;
            o.y = acc[m][n][1] + bv.y;
            o.z = acc[m][n][2] + bv.z;
            o.w = acc[m][n][3] + bv.w;
            *(float4*)&fo[(size_t)grow * 1024 + gcolb] = o;
        }
    }
}

// ---------------------------------------------------------------------------
// Flash attention (R5-verified structure): swapped QK^T + swapped PV,
// XCD-local block mapping, LDS-staged double-buffered K/V, in-register
// softmax with defer-max. grid 512 linear; 33 steps/block.
// ---------------------------------------------------------------------------
__global__ __launch_bounds__(256)
void kattn(const u16* __restrict__ Q, const u16* __restrict__ K,
           const u16* __restrict__ Vt, u16* __restrict__ Z) {
    __shared__ u16 Ks[2][64 * 64];
    __shared__ u16 Vs[2][64 * 64];
    __shared__ u16 Pl[4][16 * 72];
    const int t = threadIdx.x, l = t & 63, w = t >> 6;
    const int lq = l & 15, lg = l >> 4;

    // XCD-bijective remap: lin%8 -> xcd; want bh%8 == lin%8
    const int lin = blockIdx.x + 16 * blockIdx.y;
    const int xcd = lin & 7;
    const int idx = lin >> 3;            // 0..63
    const int pair = idx & 15;
    const int bh = xcd + 8 * (idx >> 4); // 0..31

    const size_t base = (size_t)bh * (S_ * KH);
    const u16* Qb = Q + base;
    const u16* Kb = K + base;
    const u16* Vb = Vt + base;
    const int b = bh >> 4, h = bh & 15;
    u16* Pw = &Pl[w][0];

    const int c0 = ((lg ^ (lq & 7)) * 8);
    const int c1 = c0 ^ 32;
    const float NINF = -__builtin_inff();

    auto stage = [&](int k0, int buf) {
        #pragma unroll
        for (int i = 0; i < 2; ++i) {
            const int idx2 = t + i * 256;
            const int row = idx2 >> 3;
            const int cg = (idx2 & 7) ^ (row & 7);
            __builtin_amdgcn_global_load_lds(
                (const __attribute__((address_space(1))) unsigned int*)
                    (Kb + (size_t)(k0 + row) * KH + cg * 8),
                (__attribute__((address_space(3))) unsigned int*)(&Ks[buf][idx2 * 8]),
                16, 0, 0);
            __builtin_amdgcn_global_load_lds(
                (const __attribute__((address_space(1))) unsigned int*)
                    (Vb + (size_t)row * S_ + k0 + cg * 8),
                (__attribute__((address_space(3))) unsigned int*)(&Vs[buf][idx2 * 8]),
                16, 0, 0);
        }
    };

    const float SCL = 0.18033688011112042f;   // 0.125 * log2(e)

    #pragma unroll 1
    for (int ph = 0; ph < 2; ++ph) {
        const int qt = ph ? (31 - pair) : pair;
        const int nt = qt + 1;
        const int qs = qt * 64 + w * 16;
        const int lim = w * 16 + lq;

        const s16x8 qf0 = *(const s16x8*)&Qb[(size_t)(qs + lq) * KH + lg * 8];
        const s16x8 qf1 = *(const s16x8*)&Qb[(size_t)(qs + lq) * KH + 32 + lg * 8];

        float mrow = NINF, lrow = 0.f;
        f32x4 zacc[4] = {};

        stage(0, 0);
        __syncthreads();

        for (int kt = 0; kt < nt; ++kt) {
            const int buf = kt & 1;
            if (kt + 1 < nt) stage((kt + 1) * 64, buf ^ 1);

            f32x4 sf[4] = {};
            __builtin_amdgcn_s_setprio(1);
            #pragma unroll
            for (int kf = 0; kf < 4; ++kf) {
                const int row = kf * 16 + lq;
                const s16x8 ka = *(const s16x8*)&Ks[buf][row * 64 + c0];
                const s16x8 kb = *(const s16x8*)&Ks[buf][row * 64 + c1];
                sf[kf] = __builtin_amdgcn_mfma_f32_16x16x32_bf16(ka, qf0, sf[kf], 0, 0, 0);
                sf[kf] = __builtin_amdgcn_mfma_f32_16x16x32_bf16(kb, qf1, sf[kf], 0, 0, 0);
            }
            __builtin_amdgcn_s_setprio(0);

            // lane holds S[k=16kf+4lg+r][q=lq] (log2 domain after scale)
            float p[4][4];
            const bool diag = (kt == qt);
            #pragma unroll
            for (int kf = 0; kf < 4; ++kf)
                #pragma unroll
                for (int r = 0; r < 4; ++r) {
                    float v = sf[kf][r] * SCL;
                    if (diag && (kf * 16 + lg * 4 + r) > lim) v = NINF;
                    p[kf][r] = v;
                }

            float mk[4];
            #pragma unroll
            for (int kf = 0; kf < 4; ++kf)
                mk[kf] = fmaxf(fmaxf(p[kf][0], p[kf][1]), fmaxf(p[kf][2], p[kf][3]));
            float tmax = fmaxf(fmaxf(mk[0], mk[1]), fmaxf(mk[2], mk[3]));
            tmax = fmaxf(tmax, __shfl_xor(tmax, 16));
            tmax = fmaxf(tmax, __shfl_xor(tmax, 32));

            float alpha = 1.f;
            if (!__all(tmax <= mrow + 8.f)) {
                const float nm = fmaxf(mrow, tmax);
                alpha = exp2f(mrow - nm);
                mrow = nm;
                #pragma unroll
                for (int nf = 0; nf < 4; ++nf)
                    #pragma unroll
                    for (int r = 0; r < 4; ++r)
                        zacc[nf][r] *= alpha;   // q = lq is lane-local
            }

            float sk[4];
            #pragma unroll
            for (int kf = 0; kf < 4; ++kf) {
                #pragma unroll
                for (int r = 0; r < 4; ++r)
                    p[kf][r] = exp2f(p[kf][r] - mrow);
                sk[kf] = (p[kf][0] + p[kf][1]) + (p[kf][2] + p[kf][3]);
            }
            float rsum = (sk[0] + sk[1]) + (sk[2] + sk[3]);
            rsum += __shfl_xor(rsum, 16);
            rsum += __shfl_xor(rsum, 32);
            lrow = lrow * alpha + rsum;

            // pack P; lane's k-run is contiguous -> lands in A/B-frag layout
            #pragma unroll
            for (int kf = 0; kf < 4; ++kf) {
                u32x2 wp;
                wp.x = cvt_pk_bf16(p[kf][0], p[kf][1]);
                wp.y = cvt_pk_bf16(p[kf][2], p[kf][3]);
                *(u32x2*)&Pw[lq * 72 + kf * 16 + lg * 4] = wp;
            }
            const s16x8 pa0 = *(const s16x8*)&Pw[lq * 72 + lg * 8];
            const s16x8 pa1 = *(const s16x8*)&Pw[lq * 72 + 32 + lg * 8];

            __builtin_amdgcn_s_setprio(1);
            #pragma unroll
            for (int nf = 0; nf < 4; ++nf) {
                const int row = nf * 16 + lq;
                const s16x8 v0 = *(const s16x8*)&Vs[buf][row * 64 + c0];
                const s16x8 v1 = *(const s16x8*)&Vs[buf][row * 64 + c1];
                // swapped: C[row=d][col=q] -> lane holds 4 consecutive d
                zacc[nf] = __builtin_amdgcn_mfma_f32_16x16x32_bf16(v0, pa0, zacc[nf], 0, 0, 0);
                zacc[nf] = __builtin_amdgcn_mfma_f32_16x16x32_bf16(v1, pa1, zacc[nf], 0, 0, 0);
            }
            __builtin_amdgcn_s_setprio(0);
            __syncthreads();
        }

        // zacc[nf][r] = z[q=lq][d=nf*16+lg*4+r]; lrow is lane-local
        const float rinv = 1.f / lrow;
        const size_t zrow = (size_t)(b * S_ + qs + lq) * 1024 + h * 64;
        #pragma unroll
        for (int nf = 0; nf < 4; ++nf) {
            u32x2 wp;
            wp.x = cvt_pk_bf16(zacc[nf][0] * rinv, zacc[nf][1] * rinv);
            wp.y = cvt_pk_bf16(zacc[nf][2] * rinv, zacc[nf][3] * rinv);
            *(u32x2*)&Z[zrow + nf * 16 + lg * 4] = wp;
        }
    }
}

// ---------------------------------------------------------------------------
extern "C" void kernel_launch(void* const* d_in, const int* in_sizes, int n_in,
                              void* d_out, int out_size, void* d_ws, size_t ws_size,
                              hipStream_t stream) {
    const float* x  = (const float*)d_in[0];
    const float* WQ = (const float*)d_in[1];
    const float* WK = (const float*)d_in[2];
    const float* WV = (const float*)d_in[3];
    const float* WO = (const float*)d_in[4];
    const float* bQ = (const float*)d_in[5];
    const float* bK = (const float*)d_in[6];
    const float* bV = (const float*)d_in[7];
    const float* bO = (const float*)d_in[8];
    float* out = (float*)d_out;

    u16* ws  = (u16*)d_ws;
    u16* xb  = ws;
    u16* wt  = xb + 4194304u;
    u16* Qb  = wt + 4194304u;
    u16* Kb  = Qb + 4194304u;
    u16* Vtb = Kb + 4194304u;
    u16* Zb  = Vtb + 4194304u;

    kcvt_x<<<dim3(4096), 256, 0, stream>>>(x, xb);
    ktrans_w<<<dim3(16, 16, 4), 256, 0, stream>>>(WQ, WK, WV, WO, wt);
    kgemm0t<0><<<dim3(32, 8, 2), 256, 0, stream>>>(xb, wt, bQ, bK, Qb, Kb);
    kgemm0t<1><<<dim3(32, 8, 1), 256, 0, stream>>>(
        xb, wt + 2u * 1048576u, bV, nullptr, Vtb, nullptr);
    kattn<<<dim3(16, BH_), 256, 0, stream>>>(Qb, Kb, Vtb, Zb);
    kgemm1<<<dim3(512), 256, 0, stream>>>(
        Zb, wt + 3u * 1048576u, bO, out);
}

// Round 8
// 199.810 us; speedup vs baseline: 1.1913x; 1.1159x over previous
//
#include <hip/hip_runtime.h>

typedef unsigned short u16;
typedef __attribute__((ext_vector_type(4))) float f32x4;
typedef __attribute__((ext_vector_type(8))) short s16x8;
typedef __attribute__((ext_vector_type(4))) unsigned short u16x4;
typedef __attribute__((ext_vector_type(2))) unsigned int u32x2;

#define S_ 2048
#define D_ 1024
#define H_ 16
#define KH 64
#define M_ 4096   // B*S
#define BH_ 32    // B*H

__device__ __forceinline__ float bf2f(u16 v) {
    union { unsigned int u; float f; } x; x.u = ((unsigned int)v) << 16; return x.f;
}
__device__ __forceinline__ u16 f2bf(float f) {
    union { float ff; unsigned int u; } x; x.ff = f;
    unsigned int r = x.u + 0x7fffu + ((x.u >> 16) & 1u);
    return (u16)(r >> 16);
}
__device__ __forceinline__ unsigned int cvt_pk_bf16(float lo, float hi) {
    unsigned int d;
    asm("v_cvt_pk_bf16_f32 %0, %1, %2" : "=v"(d) : "v"(lo), "v"(hi));
    return d;
}

// ---------------------------------------------------------------------------
// x (fp32, 4096x1024) -> xb (bf16)
// ---------------------------------------------------------------------------
__global__ void kcvt_x(const float* __restrict__ x, u16* __restrict__ xb) {
    const int i = (blockIdx.x * 256 + threadIdx.x) * 4;
    const float4 v = *(const float4*)&x[i];
    u16x4 o;
    o.x = f2bf(v.x); o.y = f2bf(v.y); o.z = f2bf(v.z); o.w = f2bf(v.w);
    *(u16x4*)&xb[i] = o;
}

// ---------------------------------------------------------------------------
// Weight pack (fp32 src -> bf16 dst):
//   mats 0-2: Wt[n*1024+d] = W[h=n>>6][d][k=n&63]  (n = h*64+k)
//   mat  3 : WtO[dc*1024+n] = W_O[n*1024+dc]
// ---------------------------------------------------------------------------
__global__ void ktrans_w(const float* __restrict__ WQ, const float* __restrict__ WK,
                         const float* __restrict__ WV, const float* __restrict__ WO,
                         u16* __restrict__ wt) {
    __shared__ u16 tile[64][65];
    const int mat = blockIdx.z;
    const float* src = (mat == 0) ? WQ : (mat == 1) ? WK : (mat == 2) ? WV : WO;
    u16* dst = wt + (size_t)mat * 1048576;
    const int a0 = blockIdx.x * 64, b0 = blockIdx.y * 64;
    const int t = threadIdx.x;
    const int bl = t & 63, ar = t >> 6;
    #pragma unroll
    for (int i = 0; i < 16; ++i) {
        int a = a0 + i * 4 + ar, b = b0 + bl;
        size_t sa = (mat < 3) ? (((size_t)(b >> 6)) << 16) + ((size_t)a << 6) + (b & 63)
                              : (size_t)a * 1024 + b;
        tile[i * 4 + ar][bl] = f2bf(src[sa]);
    }
    __syncthreads();
    #pragma unroll
    for (int i = 0; i < 16; ++i) {
        int bl2 = i * 4 + ar;
        dst[(size_t)(b0 + bl2) * 1024 + a0 + bl] = tile[bl][bl2];
    }
}

// ---------------------------------------------------------------------------
// QKV GEMM (R5-verified): 128x128 tile, BK=32, 4 waves (2x2), uniform swapped
// MFMA (lane holds 4 consecutive output cols). z=0/1: packed 8B stores to
// Q/K (BH,S,64). z=2: scalar stores into Vt (BH,64,S).
// ---------------------------------------------------------------------------
__global__ __launch_bounds__(256)
void kgemm0(const u16* __restrict__ A, const u16* __restrict__ Wt,
            const float* __restrict__ b0p, const float* __restrict__ b1p,
            const float* __restrict__ b2p,
            u16* __restrict__ Qo, u16* __restrict__ Ko, u16* __restrict__ Vto) {
    __shared__ u16 As[2][128 * 32];
    __shared__ u16 Bs[2][128 * 32];
    const int t = threadIdx.x;
    const int l = t & 63, w = t >> 6;
    const int lq = l & 15, lg = l >> 4;
    const int wr = w >> 1, wc = w & 1;
    const int m0 = blockIdx.x * 128;
    const int n0 = blockIdx.y * 128;
    const int z = blockIdx.z;
    const u16* Bt = Wt + (size_t)z * 1048576;
    const float* bias = (z == 0) ? b0p : (z == 1) ? b1p : b2p;

    f32x4 acc[4][4] = {};

    auto stage = [&](int kt, int buf) {
        #pragma unroll
        for (int i = 0; i < 2; ++i) {
            int idx = t + i * 256;
            int row = idx >> 2, cc = idx & 3;
            const u16* ga = A + (size_t)(m0 + row) * 1024 + kt * 32 + cc * 8;
            const u16* gb = Bt + (size_t)(n0 + row) * 1024 + kt * 32 + cc * 8;
            __builtin_amdgcn_global_load_lds(
                (const __attribute__((address_space(1))) unsigned int*)ga,
                (__attribute__((address_space(3))) unsigned int*)(&As[buf][idx * 8]),
                16, 0, 0);
            __builtin_amdgcn_global_load_lds(
                (const __attribute__((address_space(1))) unsigned int*)gb,
                (__attribute__((address_space(3))) unsigned int*)(&Bs[buf][idx * 8]),
                16, 0, 0);
        }
    };

    stage(0, 0);
    __syncthreads();
    for (int kt = 0; kt < 32; ++kt) {
        const int cur = kt & 1;
        if (kt + 1 < 32) stage(kt + 1, cur ^ 1);
        s16x8 af[4], bf[4];
        #pragma unroll
        for (int m = 0; m < 4; ++m)
            af[m] = *(const s16x8*)&As[cur][(wr * 64 + m * 16 + lq) * 32 + lg * 8];
        #pragma unroll
        for (int n = 0; n < 4; ++n)
            bf[n] = *(const s16x8*)&Bs[cur][(wc * 64 + n * 16 + lq) * 32 + lg * 8];
        #pragma unroll
        for (int m = 0; m < 4; ++m)
            #pragma unroll
            for (int n = 0; n < 4; ++n)
                acc[m][n] = __builtin_amdgcn_mfma_f32_16x16x32_bf16(
                    bf[n], af[m], acc[m][n], 0, 0, 0);   // swapped: col frag-local
        __syncthreads();
    }

    // lane holds C[gcolb..gcolb+3][grow]: 4 consecutive n-cols for one m-row
    #pragma unroll
    for (int n = 0; n < 4; ++n) {
        const int gcolb = n0 + wc * 64 + n * 16 + lg * 4;
        const float4 bv = *(const float4*)&bias[gcolb];
        const int h = gcolb >> 6, kk0 = gcolb & 63;
        #pragma unroll
        for (int m = 0; m < 4; ++m) {
            const int grow = m0 + wr * 64 + m * 16 + lq;
            const int b = grow >> 11, s = grow & 2047;
            const float v0 = acc[m][n][0] + bv.x;
            const float v1 = acc[m][n][1] + bv.y;
            const float v2 = acc[m][n][2] + bv.z;
            const float v3 = acc[m][n][3] + bv.w;
            if (z == 2) {
                // Vt[((b*16+h)*64 + kk)*2048 + s]
                u16* vb = Vto + ((size_t)((b * 16 + h) * 64 + kk0) * 2048 + s);
                vb[0] = f2bf(v0); vb[2048] = f2bf(v1);
                vb[4096] = f2bf(v2); vb[6144] = f2bf(v3);
            } else {
                u16* outp = (z == 0) ? Qo : Ko;
                u32x2 wp;
                wp.x = cvt_pk_bf16(v0, v1);
                wp.y = cvt_pk_bf16(v2, v3);
                *(u32x2*)&outp[((size_t)(b * 16 + h) * 2048 + s) * 64 + kk0] = wp;
            }
        }
    }
}

// ---------------------------------------------------------------------------
// Output GEMM: out = Z(4096x1024) * WtO^T + bO, fp32 out.
// BM=128, BN=64, 1-D grid 512 with XCD-local remap: each XCD owns 4 m-block
// rows -> A panel 1MB + B 2MB = 3MB fits XCD L2 (kills the 16x A re-read).
// ---------------------------------------------------------------------------
__global__ __launch_bounds__(256)
void kgemm1(const u16* __restrict__ A, const u16* __restrict__ Bt,
            const float* __restrict__ bias, float* __restrict__ fo) {
    __shared__ u16 As[2][128 * 32];
    __shared__ u16 Bs[2][64 * 32];
    const int t = threadIdx.x;
    const int l = t & 63, w = t >> 6;
    const int lq = l & 15, lg = l >> 4;
    const int wr = w >> 1, wc = w & 1;

    const int lin = blockIdx.x;          // 0..511
    const int xcd = lin & 7;
    const int s = lin >> 3;              // 0..63
    const int nb = s & 15;               // 16 n-blocks
    const int mb = (s >> 4) * 8 + xcd;   // 32 m-blocks, grouped per XCD
    const int m0 = mb * 128;
    const int n0 = nb * 64;

    f32x4 acc[4][2] = {};

    auto stage = [&](int kt, int buf) {
        #pragma unroll
        for (int i = 0; i < 2; ++i) {
            int idx = t + i * 256;
            int row = idx >> 2, cc = idx & 3;
            __builtin_amdgcn_global_load_lds(
                (const __attribute__((address_space(1))) unsigned int*)
                    (A + (size_t)(m0 + row) * 1024 + kt * 32 + cc * 8),
                (__attribute__((address_space(3))) unsigned int*)(&As[buf][idx * 8]),
                16, 0, 0);
        }
        {
            int row = t >> 2, cc = t & 3;
            __builtin_amdgcn_global_load_lds(
                (const __attribute__((address_space(1))) unsigned int*)
                    (Bt + (size_t)(n0 + row) * 1024 + kt * 32 + cc * 8),
                (__attribute__((address_space(3))) unsigned int*)(&Bs[buf][t * 8]),
                16, 0, 0);
        }
    };

    stage(0, 0);
    __syncthreads();
    for (int kt = 0; kt < 32; ++kt) {
        const int cur = kt & 1;
        if (kt + 1 < 32) stage(kt + 1, cur ^ 1);
        s16x8 af[4], bf[2];
        #pragma unroll
        for (int m = 0; m < 4; ++m)
            af[m] = *(const s16x8*)&As[cur][(wr * 64 + m * 16 + lq) * 32 + lg * 8];
        #pragma unroll
        for (int n = 0; n < 2; ++n)
            bf[n] = *(const s16x8*)&Bs[cur][(wc * 32 + n * 16 + lq) * 32 + lg * 8];
        #pragma unroll
        for (int m = 0; m < 4; ++m)
            #pragma unroll
            for (int n = 0; n < 2; ++n)
                acc[m][n] = __builtin_amdgcn_mfma_f32_16x16x32_bf16(
                    bf[n], af[m], acc[m][n], 0, 0, 0);
        __syncthreads();
    }

    #pragma unroll
    for (int n = 0; n < 2; ++n) {
        const int gcolb = n0 + wc * 32 + n * 16 + lg * 4;
        const float4 bv = *(const float4*)&bias[gcolb];
        #pragma unroll
        for (int m = 0; m < 4; ++m) {
            const int grow = m0 + wr * 64 + m * 16 + lq;
            float4 o;
            o.x = acc[m][n][0] + bv.x;
            o.y = acc[m][n][1] + bv.y;
            o.z = acc[m][n][2] + bv.z;
            o.w = acc[m][n][3] + bv.w;
            *(float4*)&fo[(size_t)grow * 1024 + gcolb] = o;
        }
    }
}

// ---------------------------------------------------------------------------
// Flash attention: 1024 single-qt blocks, LPT-ordered (qt descending within
// each XCD; 4 bh per XCD for K/V L2 locality). Swapped QK^T + swapped PV,
// LDS-staged double-buffered K/V, in-register softmax with defer-max.
// ---------------------------------------------------------------------------
__global__ __launch_bounds__(256)
void kattn(const u16* __restrict__ Q, const u16* __restrict__ K,
           const u16* __restrict__ Vt, u16* __restrict__ Z) {
    __shared__ u16 Ks[2][64 * 64];
    __shared__ u16 Vs[2][64 * 64];
    __shared__ u16 Pl[4][16 * 72];
    const int t = threadIdx.x, l = t & 63, w = t >> 6;
    const int lq = l & 15, lg = l >> 4;

    // LPT + XCD-local decode: lin%8 = xcd; per XCD 4 bh x 32 qt, qt descending
    const int lin = blockIdx.x;          // 0..1023
    const int xcd = lin & 7;
    const int r = lin >> 3;              // 0..127
    const int qt = 31 - (r >> 2);        // longest blocks dispatch first
    const int bh = xcd + 8 * (r & 3);    // 0..31

    const size_t base = (size_t)bh * (S_ * KH);
    const u16* Qb = Q + base;
    const u16* Kb = K + base;
    const u16* Vb = Vt + base;
    const int b = bh >> 4, h = bh & 15;
    u16* Pw = &Pl[w][0];

    const int c0 = ((lg ^ (lq & 7)) * 8);
    const int c1 = c0 ^ 32;
    const float NINF = -__builtin_inff();
    const float SCL = 0.18033688011112042f;   // 0.125 * log2(e)

    auto stage = [&](int k0, int buf) {
        #pragma unroll
        for (int i = 0; i < 2; ++i) {
            const int idx2 = t + i * 256;
            const int row = idx2 >> 3;
            const int cg = (idx2 & 7) ^ (row & 7);
            __builtin_amdgcn_global_load_lds(
                (const __attribute__((address_space(1))) unsigned int*)
                    (Kb + (size_t)(k0 + row) * KH + cg * 8),
                (__attribute__((address_space(3))) unsigned int*)(&Ks[buf][idx2 * 8]),
                16, 0, 0);
            __builtin_amdgcn_global_load_lds(
                (const __attribute__((address_space(1))) unsigned int*)
                    (Vb + (size_t)row * S_ + k0 + cg * 8),
                (__attribute__((address_space(3))) unsigned int*)(&Vs[buf][idx2 * 8]),
                16, 0, 0);
        }
    };

    const int nt = qt + 1;
    const int qs = qt * 64 + w * 16;
    const int lim = w * 16 + lq;

    const s16x8 qf0 = *(const s16x8*)&Qb[(size_t)(qs + lq) * KH + lg * 8];
    const s16x8 qf1 = *(const s16x8*)&Qb[(size_t)(qs + lq) * KH + 32 + lg * 8];

    float mrow = NINF, lrow = 0.f;
    f32x4 zacc[4] = {};

    stage(0, 0);
    __syncthreads();

    for (int kt = 0; kt < nt; ++kt) {
        const int buf = kt & 1;
        if (kt + 1 < nt) stage((kt + 1) * 64, buf ^ 1);

        f32x4 sf[4] = {};
        __builtin_amdgcn_s_setprio(1);
        #pragma unroll
        for (int kf = 0; kf < 4; ++kf) {
            const int row = kf * 16 + lq;
            const s16x8 ka = *(const s16x8*)&Ks[buf][row * 64 + c0];
            const s16x8 kb = *(const s16x8*)&Ks[buf][row * 64 + c1];
            sf[kf] = __builtin_amdgcn_mfma_f32_16x16x32_bf16(ka, qf0, sf[kf], 0, 0, 0);
            sf[kf] = __builtin_amdgcn_mfma_f32_16x16x32_bf16(kb, qf1, sf[kf], 0, 0, 0);
        }
        __builtin_amdgcn_s_setprio(0);

        // lane holds S[k=16kf+4lg+r][q=lq] (log2 domain after scale)
        float p[4][4];
        const bool diag = (kt == qt);
        #pragma unroll
        for (int kf = 0; kf < 4; ++kf)
            #pragma unroll
            for (int r2 = 0; r2 < 4; ++r2) {
                float v = sf[kf][r2] * SCL;
                if (diag && (kf * 16 + lg * 4 + r2) > lim) v = NINF;
                p[kf][r2] = v;
            }

        float mk[4];
        #pragma unroll
        for (int kf = 0; kf < 4; ++kf)
            mk[kf] = fmaxf(fmaxf(p[kf][0], p[kf][1]), fmaxf(p[kf][2], p[kf][3]));
        float tmax = fmaxf(fmaxf(mk[0], mk[1]), fmaxf(mk[2], mk[3]));
        tmax = fmaxf(tmax, __shfl_xor(tmax, 16));
        tmax = fmaxf(tmax, __shfl_xor(tmax, 32));

        float alpha = 1.f;
        if (!__all(tmax <= mrow + 8.f)) {
            const float nm = fmaxf(mrow, tmax);
            alpha = exp2f(mrow - nm);
            mrow = nm;
            #pragma unroll
            for (int nf = 0; nf < 4; ++nf)
                #pragma unroll
                for (int r2 = 0; r2 < 4; ++r2)
                    zacc[nf][r2] *= alpha;   // q = lq is lane-local
        }

        float sk[4];
        #pragma unroll
        for (int kf = 0; kf < 4; ++kf) {
            #pragma unroll
            for (int r2 = 0; r2 < 4; ++r2)
                p[kf][r2] = exp2f(p[kf][r2] - mrow);
            sk[kf] = (p[kf][0] + p[kf][1]) + (p[kf][2] + p[kf][3]);
        }
        float rsum = (sk[0] + sk[1]) + (sk[2] + sk[3]);
        rsum += __shfl_xor(rsum, 16);
        rsum += __shfl_xor(rsum, 32);
        lrow = lrow * alpha + rsum;

        // pack P; lane's k-run is contiguous -> lands in A/B-frag layout
        #pragma unroll
        for (int kf = 0; kf < 4; ++kf) {
            u32x2 wp;
            wp.x = cvt_pk_bf16(p[kf][0], p[kf][1]);
            wp.y = cvt_pk_bf16(p[kf][2], p[kf][3]);
            *(u32x2*)&Pw[lq * 72 + kf * 16 + lg * 4] = wp;
        }
        const s16x8 pa0 = *(const s16x8*)&Pw[lq * 72 + lg * 8];
        const s16x8 pa1 = *(const s16x8*)&Pw[lq * 72 + 32 + lg * 8];

        __builtin_amdgcn_s_setprio(1);
        #pragma unroll
        for (int nf = 0; nf < 4; ++nf) {
            const int row = nf * 16 + lq;
            const s16x8 v0 = *(const s16x8*)&Vs[buf][row * 64 + c0];
            const s16x8 v1 = *(const s16x8*)&Vs[buf][row * 64 + c1];
            // swapped: C[row=d][col=q] -> lane holds 4 consecutive d
            zacc[nf] = __builtin_amdgcn_mfma_f32_16x16x32_bf16(v0, pa0, zacc[nf], 0, 0, 0);
            zacc[nf] = __builtin_amdgcn_mfma_f32_16x16x32_bf16(v1, pa1, zacc[nf], 0, 0, 0);
        }
        __builtin_amdgcn_s_setprio(0);
        __syncthreads();
    }

    // zacc[nf][r] = z[q=lq][d=nf*16+lg*4+r]; lrow is lane-local
    const float rinv = 1.f / lrow;
    const size_t zrow = (size_t)(b * S_ + qs + lq) * 1024 + h * 64;
    #pragma unroll
    for (int nf = 0; nf < 4; ++nf) {
        u32x2 wp;
        wp.x = cvt_pk_bf16(zacc[nf][0] * rinv, zacc[nf][1] * rinv);
        wp.y = cvt_pk_bf16(zacc[nf][2] * rinv, zacc[nf][3] * rinv);
        *(u32x2*)&Z[zrow + nf * 16 + lg * 4] = wp;
    }
}

// ---------------------------------------------------------------------------
extern "C" void kernel_launch(void* const* d_in, const int* in_sizes, int n_in,
                              void* d_out, int out_size, void* d_ws, size_t ws_size,
                              hipStream_t stream) {
    const float* x  = (const float*)d_in[0];
    const float* WQ = (const float*)d_in[1];
    const float* WK = (const float*)d_in[2];
    const float* WV = (const float*)d_in[3];
    const float* WO = (const float*)d_in[4];
    const float* bQ = (const float*)d_in[5];
    const float* bK = (const float*)d_in[6];
    const float* bV = (const float*)d_in[7];
    const float* bO = (const float*)d_in[8];
    float* out = (float*)d_out;

    u16* ws  = (u16*)d_ws;
    u16* xb  = ws;
    u16* wt  = xb + 4194304u;
    u16* Qb  = wt + 4194304u;
    u16* Kb  = Qb + 4194304u;
    u16* Vtb = Kb + 4194304u;
    u16* Zb  = Vtb + 4194304u;

    kcvt_x<<<dim3(4096), 256, 0, stream>>>(x, xb);
    ktrans_w<<<dim3(16, 16, 4), 256, 0, stream>>>(WQ, WK, WV, WO, wt);
    kgemm0<<<dim3(32, 8, 3), 256, 0, stream>>>(
        xb, wt, bQ, bK, bV, Qb, Kb, Vtb);
    kattn<<<dim3(1024), 256, 0, stream>>>(Qb, Kb, Vtb, Zb);
    kgemm1<<<dim3(512), 256, 0, stream>>>(
        Zb, wt + 3u * 1048576u, bO, out);
}